// Round 5
// baseline (134.240 us; speedup 1.0000x reference)
//
#include <hip/hip_runtime.h>
#include <math.h>

#define NDIM 1024
#define HDIM 128
#define NB 256
#define NT 72
#define NR 36
#define NBLK 256
#define NTHR 512

__device__ __forceinline__ float wave_sum(float v) {
#pragma unroll
  for (int off = 32; off > 0; off >>= 1) v += __shfl_down(v, off, 64);
  return v;
}

__device__ __forceinline__ float dot4(const float4 a, const float4 b) {
  return a.x * b.x + a.y * b.y + a.z * b.z + a.w * b.w;
}

// Software grid barrier: all 256 blocks are co-resident (1-2 blocks/CU by
// resource math), monotone counter, agent-scope release/acquire.
__device__ __forceinline__ void grid_barrier(unsigned int* cnt, unsigned int target) {
  __syncthreads();
  if (threadIdx.x == 0) {
    __hip_atomic_fetch_add(cnt, 1u, __ATOMIC_RELEASE, __HIP_MEMORY_SCOPE_AGENT);
    while (__hip_atomic_load(cnt, __ATOMIC_ACQUIRE, __HIP_MEMORY_SCOPE_AGENT) < target)
      __builtin_amdgcn_s_sleep(8);
  }
  __syncthreads();
}

// ws float offsets
#define OFF_FS 0u
#define OFF_FQ 524288u
#define OFF_MS 1048576u
#define OFF_REPR 1572864u
#define OFF_IMGN 1835008u
#define OFF_POOL 2097152u
#define OFF_U 2359296u
#define OFF_A 2621440u
#define OFF_BV 2883584u
#define OFF_HP 3145728u
#define OFF_PN 3670016u
#define OFF_PD 4718592u
#define OFF_MEAN 5767168u
#define OFF_RSTD 5768192u
#define OFF_CP 5769216u
#define OFF_EP 5771264u
#define CNT_BYTE_OFF (5773312u * 4u)

__global__ __launch_bounds__(NTHR) void k_mega(
    const float* __restrict__ img, const float* __restrict__ cap, const int* __restrict__ lens,
    const float* __restrict__ Wg1, const float* __restrict__ bg1, const float* __restrict__ Wg2,
    const float* __restrict__ bg2, const float* __restrict__ Wb1, const float* __restrict__ bb1,
    const float* __restrict__ Wb2, const float* __restrict__ bb2, float* ws,
    float* __restrict__ out, unsigned int* cnt) {
  __shared__ float smem[17408];  // 69.6 KB, reused per phase
  __shared__ float sredbuf[32];
  __shared__ float sval;

  const int bid = blockIdx.x, tid = threadIdx.x;
  const int lane = tid & 63, wv = tid >> 6;

  float* fs = ws + OFF_FS;      // [512][1024] (half-major)
  float* fq = ws + OFF_FQ;
  float* ms = ws + OFF_MS;
  float* repr = ws + OFF_REPR;  // [256][1024]
  float* imgn = ws + OFF_IMGN;
  float* pooled = ws + OFF_POOL;
  float* uarr = ws + OFF_U;
  float* aarr = ws + OFF_A;
  float* bvarr = ws + OFF_BV;
  float* hpart = ws + OFF_HP;   // [16][256][128]
  float* pn = ws + OFF_PN;      // [16][256][256]
  float* pd = ws + OFF_PD;
  float* meanv = ws + OFF_MEAN;
  float* rstdv = ws + OFF_RSTD;
  float* cpart = ws + OFF_CP;   // [8][256]
  float* epart = ws + OFF_EP;

  // ================= P0: cap scan + image mean/l2norm (block = b) =========
  {
    const int b = bid;
    const int len = lens[b];
    const int th = tid >> 8;          // time half 0/1
    const int c4 = (tid & 255) * 4;
    const int t0 = th * 36;
    const float* base = cap + (size_t)b * NT * NDIM + (size_t)t0 * NDIM + c4;
    float fsx = 0.f, fsy = 0.f, fsz = 0.f, fsw = 0.f;
    float fqx = 0.f, fqy = 0.f, fqz = 0.f, fqw = 0.f;
    float msx = 0.f, msy = 0.f, msz = 0.f, msw = 0.f;
#pragma unroll 6
    for (int tt = 0; tt < 36; ++tt) {
      const float4 v = *reinterpret_cast<const float4*>(base + tt * NDIM);
      fsx += v.x; fsy += v.y; fsz += v.z; fsw += v.w;
      fqx += v.x * v.x; fqy += v.y * v.y; fqz += v.z * v.z; fqw += v.w * v.w;
      if (t0 + tt < len) { msx += v.x; msy += v.y; msz += v.z; msw += v.w; }
    }
    const size_t o = (size_t)(th * NB + b) * NDIM + c4;
    *reinterpret_cast<float4*>(fs + o) = make_float4(fsx, fsy, fsz, fsw);
    *reinterpret_cast<float4*>(fq + o) = make_float4(fqx, fqy, fqz, fqw);
    *reinterpret_cast<float4*>(ms + o) = make_float4(msx, msy, msz, msw);

    // image mean
    const int rh = tid >> 8;  // region half: rows rh*18..+17
    const float* ibase = img + (size_t)b * NR * NDIM + (size_t)rh * 18 * NDIM + c4;
    float sx = 0.f, sy = 0.f, sz = 0.f, sw = 0.f;
#pragma unroll 6
    for (int r = 0; r < 18; ++r) {
      const float4 v = *reinterpret_cast<const float4*>(ibase + r * NDIM);
      sx += v.x; sy += v.y; sz += v.z; sw += v.w;
    }
    float4* simg = reinterpret_cast<float4*>(smem);  // [2][256]
    simg[rh * 256 + (tid & 255)] = make_float4(sx, sy, sz, sw);
    __syncthreads();
    float4 mv = make_float4(0.f, 0.f, 0.f, 0.f);
    float nsq = 0.f;
    if (tid < 256) {
      const float4 a = simg[tid], b4 = simg[256 + tid];
      const float inv = 1.0f / (float)NR;
      mv = make_float4((a.x + b4.x) * inv, (a.y + b4.y) * inv, (a.z + b4.z) * inv,
                       (a.w + b4.w) * inv);
      *reinterpret_cast<float4*>(repr + (size_t)b * NDIM + tid * 4) = mv;
      nsq = mv.x * mv.x + mv.y * mv.y + mv.z * mv.z + mv.w * mv.w;
    }
    const float sq = wave_sum(nsq);
    if (lane == 0) sredbuf[wv] = sq;
    __syncthreads();
    if (tid == 0) sval = 1.0f / (sqrtf(sredbuf[0] + sredbuf[1] + sredbuf[2] + sredbuf[3]) + 1e-8f);
    __syncthreads();
    if (tid < 256) {
      const float iv = sval;
      *reinterpret_cast<float4*>(imgn + (size_t)b * NDIM + tid * 4) =
          make_float4(mv.x * iv, mv.y * iv, mv.z * iv, mv.w * iv);
    }
  }
  grid_barrier(cnt, 1 * NBLK);

  // ================= P1: BN stats (blocks 0..15) + layer1 (all blocks) =====
  if (bid < 16) {
    const int d0 = bid * 64;
    const int dloc = tid & 63, rg = tid >> 6;  // 8 row-groups x 64 rows
    float s = 0.f, q = 0.f;
    const int r0 = rg * 64;
#pragma unroll 8
    for (int r = r0; r < r0 + 64; ++r) {
      s += fs[(size_t)r * NDIM + d0 + dloc];
      q += fq[(size_t)r * NDIM + d0 + dloc];
    }
    float* sps = smem;         // [8][64]
    float* spq = smem + 512;   // [8][64]
    sps[rg * 64 + dloc] = s;
    spq[rg * 64 + dloc] = q;
    __syncthreads();
    if (tid < 64) {
      float S = 0.f, Q = 0.f;
#pragma unroll
      for (int g2 = 0; g2 < 8; ++g2) { S += sps[g2 * 64 + tid]; Q += spq[g2 * 64 + tid]; }
      const float invN = 1.0f / (float)(NB * NT);
      const float mu = S * invN;
      const float var = Q * invN - mu * mu;
      meanv[d0 + tid] = mu;
      rstdv[d0 + tid] = 1.0f / sqrtf(var + 1e-5f);
    }
    __syncthreads();
  }
  {
    // layer1: block = (g 0..31, ks 0..7); 8 images x 128 h x 128-d slab, 2 br
    const int g = bid >> 3, ks = bid & 7;
    const int b0 = g * 8, kbase = ks * 128;
    float* shr = smem;           // [8][128]
    float* sacc = smem + 1024;   // [8][128][8]
    {
      const int im = tid >> 6, c2 = (tid & 63) * 2;
      *reinterpret_cast<float2*>(shr + im * 128 + c2) =
          *reinterpret_cast<const float2*>(repr + (size_t)(b0 + im) * NDIM + kbase + c2);
    }
    __syncthreads();
    const int h2 = tid & 63;
    const int ksub = tid >> 6;
    for (int br = 0; br < 2; ++br) {
      const float* W = br ? Wb1 : Wg1;
      float acc0[8] = {0, 0, 0, 0, 0, 0, 0, 0}, acc1[8] = {0, 0, 0, 0, 0, 0, 0, 0};
#pragma unroll
      for (int q = 0; q < 4; ++q) {
        const int dl = ksub * 16 + q * 4;
        const float* wq = W + (size_t)(kbase + dl) * HDIM + h2;
        const float wa0 = wq[0], wa1 = wq[128], wa2 = wq[256], wa3 = wq[384];
        const float wb0 = wq[64], wb1v = wq[192], wb2v = wq[320], wb3v = wq[448];
#pragma unroll
        for (int i = 0; i < 8; ++i) {
          const float4 sv = *reinterpret_cast<const float4*>(shr + i * 128 + dl);
          acc0[i] += sv.x * wa0 + sv.y * wa1 + sv.z * wa2 + sv.w * wa3;
          acc1[i] += sv.x * wb0 + sv.y * wb1v + sv.z * wb2v + sv.w * wb3v;
        }
      }
#pragma unroll
      for (int i = 0; i < 8; ++i) {
        sacc[((size_t)ksub * 128 + h2) * 8 + i] = acc0[i];
        sacc[((size_t)ksub * 128 + h2 + 64) * 8 + i] = acc1[i];
      }
      __syncthreads();
#pragma unroll
      for (int v = tid; v < 1024; v += NTHR) {
        const int hh = v & 127, im = v >> 7;
        float s = 0.f;
#pragma unroll
        for (int k2 = 0; k2 < 8; ++k2) s += sacc[((size_t)k2 * 128 + hh) * 8 + im];
        hpart[(((size_t)ks * 2 + br) * NB + b0 + im) * HDIM + hh] = s;
      }
      __syncthreads();
    }
  }
  grid_barrier(cnt, 2 * NBLK);

  // ================= P2: pooled (block=b) + layer2/derived =================
  {
    if (tid < 256) {
      const float invl = 1.0f / (float)lens[bid];
      const int d = tid * 4;
      const float4 m0 = *reinterpret_cast<const float4*>(ms + (size_t)bid * NDIM + d);
      const float4 m1 = *reinterpret_cast<const float4*>(ms + (size_t)(NB + bid) * NDIM + d);
      const float4 mu = *reinterpret_cast<const float4*>(meanv + d);
      const float4 rs = *reinterpret_cast<const float4*>(rstdv + d);
      *reinterpret_cast<float4*>(pooled + (size_t)bid * NDIM + d) =
          make_float4(((m0.x + m1.x) * invl - mu.x) * rs.x, ((m0.y + m1.y) * invl - mu.y) * rs.y,
                      ((m0.z + m1.z) * invl - mu.z) * rs.z, ((m0.w + m1.w) * invl - mu.w) * rs.w);
    }
    // layer2: block = (gb 0..31, dgrp 0..7): 8 images x 128-d slab
    const int gb = bid >> 3, dgrp = bid & 7;
    const int b0 = gb * 8;
    float* shh = smem;  // [2][8][128]
    for (int v = tid; v < 2048; v += NTHR) {
      const int brv = v >> 10, rem = v & 1023, im = rem >> 7, hh = rem & 127;
      float s = 0.f;
#pragma unroll
      for (int k2 = 0; k2 < 8; ++k2)
        s += hpart[(((size_t)k2 * 2 + brv) * NB + b0 + im) * HDIM + hh];
      s += brv ? bb1[hh] : bg1[hh];
      shh[v] = fmaxf(s, 0.f);
    }
    __syncthreads();
    const int dl = tid & 127, ig = tid >> 7;  // images b0+ig, b0+ig+4
    const int d = dgrp * 128 + dl;
    float ga0 = 0.f, ba0 = 0.f, ga1 = 0.f, ba1 = 0.f;
#pragma unroll 4
    for (int q = 0; q < 32; ++q) {
      const int h = q * 4;
      const float* wgp = Wg2 + (size_t)h * NDIM + d;
      const float* wbp = Wb2 + (size_t)h * NDIM + d;
      const float wg0 = wgp[0], wg1v = wgp[1024], wg2v = wgp[2048], wg3v = wgp[3072];
      const float wb0 = wbp[0], wb1v = wbp[1024], wb2v = wbp[2048], wb3v = wbp[3072];
      const float4 hgA = *reinterpret_cast<const float4*>(shh + (0 * 8 + ig) * 128 + h);
      const float4 hbA = *reinterpret_cast<const float4*>(shh + (1 * 8 + ig) * 128 + h);
      const float4 hgB = *reinterpret_cast<const float4*>(shh + (0 * 8 + ig + 4) * 128 + h);
      const float4 hbB = *reinterpret_cast<const float4*>(shh + (1 * 8 + ig + 4) * 128 + h);
      ga0 += hgA.x * wg0 + hgA.y * wg1v + hgA.z * wg2v + hgA.w * wg3v;
      ba0 += hbA.x * wb0 + hbA.y * wb1v + hbA.z * wb2v + hbA.w * wb3v;
      ga1 += hgB.x * wg0 + hgB.y * wg1v + hgB.z * wg2v + hgB.w * wg3v;
      ba1 += hbB.x * wb0 + hbB.y * wb1v + hbB.z * wb2v + hbB.w * wb3v;
    }
    const float bg2v = bg2[d], bb2v = bb2[d];
    float cA, eA, cB, eB;
    {
      const float ox = ga0 + bg2v + 1.0f, tb = ba0 + bb2v;
      const size_t o = (size_t)(b0 + ig) * NDIM + d;
      const float nv = imgn[o];
      uarr[o] = nv * ox;
      aarr[o] = ox * ox;
      bvarr[o] = 2.0f * ox * tb;
      cA = nv * tb;
      eA = tb * tb;
    }
    {
      const float ox = ga1 + bg2v + 1.0f, tb = ba1 + bb2v;
      const size_t o = (size_t)(b0 + ig + 4) * NDIM + d;
      const float nv = imgn[o];
      uarr[o] = nv * ox;
      aarr[o] = ox * ox;
      bvarr[o] = 2.0f * ox * tb;
      cB = nv * tb;
      eB = tb * tb;
    }
    cA = wave_sum(cA); eA = wave_sum(eA);
    cB = wave_sum(cB); eB = wave_sum(eB);
    if (lane == 0) {
      sredbuf[wv * 4 + 0] = cA; sredbuf[wv * 4 + 1] = eA;
      sredbuf[wv * 4 + 2] = cB; sredbuf[wv * 4 + 3] = eB;
    }
    __syncthreads();
    if (tid < 16) {
      const int im = tid >> 1, isE = tid & 1;
      const int ig2 = im & 3, off = (im >> 2) * 2 + isE;
      const float v = sredbuf[(ig2 * 2) * 4 + off] + sredbuf[(ig2 * 2 + 1) * 4 + off];
      (isE ? epart : cpart)[dgrp * NB + b0 + im] = v;
    }
  }
  grid_barrier(cnt, 3 * NBLK);

  // ================= P3: 3-dot sim tiles, 64x64, split-K=16 ================
  {
    const int i0 = (bid & 3) * 64, j0 = ((bid >> 2) & 3) * 64, s = bid >> 4;
    const int k0 = s * 64;
    float* su = smem;             // [64][68]
    float* sa = smem + 4352;
    float* sb = smem + 8704;
    float* sp = smem + 13056;
    const int lr = tid >> 3, lc4 = (tid & 7) * 4;
#pragma unroll
    for (int rep = 0; rep < 2; ++rep) {
      const int c = lc4 + rep * 32;
      *reinterpret_cast<float4*>(su + lr * 68 + c) =
          *reinterpret_cast<const float4*>(uarr + (size_t)(i0 + lr) * NDIM + k0 + c);
      *reinterpret_cast<float4*>(sa + lr * 68 + c) =
          *reinterpret_cast<const float4*>(aarr + (size_t)(i0 + lr) * NDIM + k0 + c);
      *reinterpret_cast<float4*>(sb + lr * 68 + c) =
          *reinterpret_cast<const float4*>(bvarr + (size_t)(i0 + lr) * NDIM + k0 + c);
      *reinterpret_cast<float4*>(sp + lr * 68 + c) =
          *reinterpret_cast<const float4*>(pooled + (size_t)(j0 + lr) * NDIM + k0 + c);
    }
    __syncthreads();
    const int tx = tid & 31, ty = tid >> 5;  // i: tx+32m, j: ty+16n
    float an[2][4] = {{0.f}}, ad[2][4] = {{0.f}};
#pragma unroll
    for (int dd = 0; dd < 64; dd += 4) {
      float4 rp[4], rq[4];
#pragma unroll
      for (int n = 0; n < 4; ++n) {
        rp[n] = *reinterpret_cast<const float4*>(sp + (ty + 16 * n) * 68 + dd);
        rq[n] = make_float4(rp[n].x * rp[n].x, rp[n].y * rp[n].y, rp[n].z * rp[n].z,
                            rp[n].w * rp[n].w);
      }
#pragma unroll
      for (int m = 0; m < 2; ++m) {
        const float4 ru = *reinterpret_cast<const float4*>(su + (tx + 32 * m) * 68 + dd);
        const float4 ra = *reinterpret_cast<const float4*>(sa + (tx + 32 * m) * 68 + dd);
        const float4 rb = *reinterpret_cast<const float4*>(sb + (tx + 32 * m) * 68 + dd);
#pragma unroll
        for (int n = 0; n < 4; ++n) {
          an[m][n] += dot4(ru, rp[n]);
          ad[m][n] += dot4(ra, rq[n]) + dot4(rb, rp[n]);
        }
      }
    }
#pragma unroll
    for (int m = 0; m < 2; ++m) {
#pragma unroll
      for (int n = 0; n < 4; ++n) {
        const int i = i0 + tx + 32 * m, j = j0 + ty + 16 * n;
        const size_t o = ((size_t)s * NB + j) * NB + i;
        pn[o] = an[m][n];
        pd[o] = ad[m][n];
      }
    }
  }
  grid_barrier(cnt, 4 * NBLK);

  // ================= P4: split-K combine + epilogue (block = caption j) ====
  if (tid < 256) {
    const int j = bid, i = tid;
    const size_t base = (size_t)j * NB + i;
    float n = 0.f, dsum = 0.f;
#pragma unroll
    for (int s = 0; s < 16; ++s) {
      n += pn[base + (size_t)s * (NB * NB)];
      dsum += pd[base + (size_t)s * (NB * NB)];
    }
    float cv = 0.f, ev = 0.f;
#pragma unroll
    for (int s8 = 0; s8 < 8; ++s8) { cv += cpart[s8 * NB + i]; ev += epart[s8 * NB + i]; }
    out[base] = (n + cv) / (sqrtf(fmaxf(dsum + ev, 0.0f)) + 1e-8f);
  }
}

extern "C" void kernel_launch(void* const* d_in, const int* in_sizes, int n_in,
                              void* d_out, int out_size, void* d_ws, size_t ws_size,
                              hipStream_t stream) {
  const float* img = (const float*)d_in[0];
  const float* cap = (const float*)d_in[1];
  const int* lens = (const int*)d_in[2];
  const float* Wg1 = (const float*)d_in[3];
  const float* bg1 = (const float*)d_in[4];
  const float* Wg2 = (const float*)d_in[5];
  const float* bg2 = (const float*)d_in[6];
  const float* Wb1 = (const float*)d_in[7];
  const float* bb1 = (const float*)d_in[8];
  const float* Wb2 = (const float*)d_in[9];
  const float* bb2 = (const float*)d_in[10];
  float* out = (float*)d_out;
  float* ws = (float*)d_ws;
  unsigned int* cnt = (unsigned int*)((char*)d_ws + CNT_BYTE_OFF);

  hipMemsetAsync(cnt, 0, 256, stream);
  hipLaunchKernelGGL(k_mega, dim3(NBLK), dim3(NTHR), 0, stream, img, cap, lens, Wg1, bg1, Wg2,
                     bg2, Wb1, bb1, Wb2, bb2, ws, out, cnt);
}